// Round 19
// baseline (353.288 us; speedup 1.0000x reference)
//
#include <hip/hip_runtime.h>
#include <math.h>

#define DEV __device__ __forceinline__

constexpr int DI = 192, Nn = 16, Rr = 6;
constexpr int Cc = 96;
constexpr int Ll = 4096;           // 64*64
constexpr int NC = 64;             // scan chunks of 64 steps

DEV float silu_(float x) { return x / (1.f + __expf(-x)); }
DEV float qadd1(float v) {
  int i = __builtin_amdgcn_mov_dpp(__float_as_int(v), 0xB1, 0xF, 0xF, true);
  return v + __int_as_float(i);
}
DEV float qadd2(float v) {
  int i = __builtin_amdgcn_mov_dpp(__float_as_int(v), 0x4E, 0xF, 0xF, true);
  return v + __int_as_float(i);
}

// ---------------- register-tiled 1x1 conv (fp32 micro-GEMM), TRANSPOSED weights [j4][oc] ----------------
template<int CIN, int COUT, int CB, int PXB, int IN_MODE, int OUT_MODE, int ACT, int HAS_BIAS, int LN>
__global__ void conv1x1v2_kernel(const float* __restrict__ in, const float4* __restrict__ wt,
                                 const float* __restrict__ bias, float* __restrict__ out,
                                 float* __restrict__ out2, const float* __restrict__ lng,
                                 const float* __restrict__ lnb) {
  constexpr int J4 = CIN / 4, STR = J4 + 1, CCN = CB / 16, PXT = PXB / 16;
  constexpr int NPB = 8192 / PXB;
  __shared__ float4 xv[PXB * STR];
  int t = threadIdx.x;
  int pb = blockIdx.x % NPB;
  int cbase = (blockIdx.x / NPB) * CB;
  int pbase = pb * PXB;
  if (IN_MODE == 0) {
    for (int idx = t; idx < PXB * J4; idx += 256) {
      int px = idx / J4, j4 = idx - px * J4;
      xv[px * STR + j4] = ((const float4*)in)[(size_t)(pbase + px) * J4 + j4];
    }
  } else {
    for (int idx = t; idx < PXB * CIN; idx += 256) {
      int px = idx & (PXB - 1), c = idx / PXB;
      int gp = pbase + px; int b = gp >> 12, p = gp & 4095;
      ((float*)xv)[px * (STR * 4) + c] = in[((size_t)b * CIN + c) * Ll + p];
    }
  }
  __syncthreads();
  if constexpr (LN) {
    constexpr int TPX = 256 / PXB;
    constexpr int CHUNK = CIN / TPX;
    int px = t / TPX, sub = t % TPX;
    float* row = (float*)(xv + px * STR);
    float sm = 0.f, sq = 0.f;
    #pragma unroll
    for (int j2 = 0; j2 < CHUNK; ++j2) {
      float v = row[sub + j2 * TPX];
      sm += v; sq += v * v;
    }
    #pragma unroll
    for (int m = 1; m < TPX; m <<= 1) {
      sm += __shfl_xor(sm, m, 64);
      sq += __shfl_xor(sq, m, 64);
    }
    float mean = sm * (1.f / CIN);
    float rs = rsqrtf(sq * (1.f / CIN) - mean * mean + 1e-6f);
    #pragma unroll
    for (int j2 = 0; j2 < CHUNK; ++j2) {
      int j = sub + j2 * TPX;
      row[j] = (row[j] - mean) * rs * lng[j] + lnb[j];
    }
    __syncthreads();
  }
  int g = t >> 4, ci = t & 15;
  float acc[PXT][CCN];
  #pragma unroll
  for (int cc = 0; cc < CCN; ++cc) {
    float b0 = HAS_BIAS ? bias[cbase + ci + 16 * cc] : 0.f;
    #pragma unroll
    for (int p = 0; p < PXT; ++p) acc[p][cc] = b0;
  }
  #pragma unroll 2
  for (int j4 = 0; j4 < J4; ++j4) {
    float4 xr[PXT];
    #pragma unroll
    for (int p = 0; p < PXT; ++p) xr[p] = xv[(g + 16 * p) * STR + j4];
    #pragma unroll
    for (int cc = 0; cc < CCN; ++cc) {
      float4 w4 = wt[(size_t)j4 * COUT + cbase + ci + 16 * cc];
      #pragma unroll
      for (int p = 0; p < PXT; ++p)
        acc[p][cc] += xr[p].x * w4.x + xr[p].y * w4.y + xr[p].z * w4.z + xr[p].w * w4.w;
    }
  }
  #pragma unroll
  for (int p = 0; p < PXT; ++p) {
    int gp = pbase + g + 16 * p;
    #pragma unroll
    for (int cc = 0; cc < CCN; ++cc) {
      int c = cbase + ci + 16 * cc;
      float v = acc[p][cc];
      if (OUT_MODE == 2) {
        if (c < 192) out[(size_t)gp * 192 + c] = v;
        else out2[(size_t)gp * 192 + (c - 192)] = silu_(v);
      } else {
        if (ACT == 1) v = silu_(v);
        if (OUT_MODE == 0) out[(size_t)gp * COUT + c] = v;
        else { int bb = gp >> 12, p2 = gp & 4095; out[((size_t)bb * COUT + c) * Ll + p2] = v; }
      }
    }
  }
}

// ---------------- FUSED attention tail: ycomb + out_proj + resln ----------------
__global__ void outproj_fused_kernel(
    const float* __restrict__ outy, const float* __restrict__ zs,
    const float* __restrict__ ong, const float* __restrict__ onb,
    const float4* __restrict__ wt, const float* __restrict__ input,
    const float* __restrict__ fftout, const float* __restrict__ ss,
    const float* __restrict__ ln2g, const float* __restrict__ ln2b,
    float* __restrict__ xres, float* __restrict__ xn2) {
  __shared__ float4 xv[32 * 49];
  int t = threadIdx.x;
  int pbase = blockIdx.x * 32;
  {
    int px = t >> 3, sub = t & 7;
    int pix = pbase + px;
    int p = pix & 4095, b = pix >> 12;
    int pt = ((p & 63) << 6) | (p >> 6);
    size_t base = (size_t)b * 4 * Ll * DI;
    const float* y0 = outy + base + (size_t)p * DI;
    const float* y1 = outy + base + ((size_t)Ll + pt) * DI;
    const float* y2 = outy + base + ((size_t)2 * Ll + (4095 - p)) * DI;
    const float* y3 = outy + base + ((size_t)3 * Ll + (4095 - pt)) * DI;
    float v[24];
    float sm = 0.f, sq = 0.f;
    #pragma unroll
    for (int j = 0; j < 24; ++j) {
      int c = sub + 8 * j;
      float vv = y0[c] + y1[c] + y2[c] + y3[c];
      v[j] = vv; sm += vv; sq += vv * vv;
    }
    #pragma unroll
    for (int m = 1; m < 8; m <<= 1) {
      sm += __shfl_xor(sm, m, 64);
      sq += __shfl_xor(sq, m, 64);
    }
    float mean = sm * (1.f / 192.f);
    float rs = rsqrtf(sq * (1.f / 192.f) - mean * mean + 1e-5f);
    const float* zrow = zs + (size_t)pix * DI;
    float* row = (float*)(xv + px * 49);
    #pragma unroll
    for (int j = 0; j < 24; ++j) {
      int c = sub + 8 * j;
      row[c] = ((v[j] - mean) * rs * ong[c] + onb[c]) * zrow[c];
    }
  }
  __syncthreads();
  int g = t >> 4, ci = t & 15;
  float acc[2][6];
  #pragma unroll
  for (int pI = 0; pI < 2; ++pI)
    #pragma unroll
    for (int cc = 0; cc < 6; ++cc) acc[pI][cc] = 0.f;
  #pragma unroll 2
  for (int j4 = 0; j4 < 48; ++j4) {
    float4 xr0 = xv[g * 49 + j4];
    float4 xr1 = xv[(g + 16) * 49 + j4];
    #pragma unroll
    for (int cc = 0; cc < 6; ++cc) {
      float4 w4 = wt[(size_t)j4 * 96 + ci + 16 * cc];
      acc[0][cc] += xr0.x * w4.x + xr0.y * w4.y + xr0.z * w4.z + xr0.w * w4.w;
      acc[1][cc] += xr1.x * w4.x + xr1.y * w4.y + xr1.z * w4.z + xr1.w * w4.w;
    }
  }
  #pragma unroll
  for (int pI = 0; pI < 2; ++pI) {
    int gp = pbase + g + 16 * pI;
    float vv[6];
    float sm = 0.f, sq = 0.f;
    #pragma unroll
    for (int cc = 0; cc < 6; ++cc) {
      int c = ci + 16 * cc;
      float x = input[(size_t)gp * Cc + c] * ss[c] + acc[pI][cc] + fftout[(size_t)gp * Cc + c];
      vv[cc] = x; sm += x; sq += x * x;
    }
    #pragma unroll
    for (int m = 1; m < 16; m <<= 1) {
      sm += __shfl_xor(sm, m, 64);
      sq += __shfl_xor(sq, m, 64);
    }
    float mean = sm * (1.f / 96.f);
    float rs = rsqrtf(sq * (1.f / 96.f) - mean * mean + 1e-5f);
    #pragma unroll
    for (int cc = 0; cc < 6; ++cc) {
      int c = ci + 16 * cc;
      xres[(size_t)gp * Cc + c] = vv[cc];
      xn2[(size_t)gp * Cc + c] = (vv[cc] - mean) * rs * ln2g[c] + ln2b[c];
    }
  }
}

// ---------------- mg_out conv + fused channel-partial sums ----------------
__global__ void mgout_fused_kernel(const float* __restrict__ in, const float4* __restrict__ wt,
                                   float* __restrict__ out, float* __restrict__ cap) {
  __shared__ float4 xv[32 * 49];
  __shared__ float redc[4][96];
  int t = threadIdx.x;
  int pbase = blockIdx.x * 32;
  for (int idx = t; idx < 32 * 48; idx += 256) {
    int px = idx / 48, j4 = idx - px * 48;
    xv[px * 49 + j4] = ((const float4*)in)[(size_t)(pbase + px) * 48 + j4];
  }
  __syncthreads();
  int g = t >> 4, ci = t & 15;
  float acc[2][6];
  #pragma unroll
  for (int pI = 0; pI < 2; ++pI)
    #pragma unroll
    for (int cc = 0; cc < 6; ++cc) acc[pI][cc] = 0.f;
  #pragma unroll 2
  for (int j4 = 0; j4 < 48; ++j4) {
    float4 xr0 = xv[g * 49 + j4];
    float4 xr1 = xv[(g + 16) * 49 + j4];
    #pragma unroll
    for (int cc = 0; cc < 6; ++cc) {
      float4 w4 = wt[(size_t)j4 * 96 + ci + 16 * cc];
      acc[0][cc] += xr0.x * w4.x + xr0.y * w4.y + xr0.z * w4.z + xr0.w * w4.w;
      acc[1][cc] += xr1.x * w4.x + xr1.y * w4.y + xr1.z * w4.z + xr1.w * w4.w;
    }
  }
  float ps[6];
  #pragma unroll
  for (int cc = 0; cc < 6; ++cc) ps[cc] = acc[0][cc] + acc[1][cc];
  #pragma unroll
  for (int pI = 0; pI < 2; ++pI) {
    int gp = pbase + g + 16 * pI;
    #pragma unroll
    for (int cc = 0; cc < 6; ++cc)
      out[(size_t)gp * 96 + ci + 16 * cc] = acc[pI][cc];
  }
  #pragma unroll
  for (int cc = 0; cc < 6; ++cc) {
    ps[cc] += __shfl_xor(ps[cc], 16, 64);
    ps[cc] += __shfl_xor(ps[cc], 32, 64);
  }
  if ((t & 63) < 16) {
    #pragma unroll
    for (int cc = 0; cc < 6; ++cc) redc[t >> 6][ci + 16 * cc] = ps[cc];
  }
  __syncthreads();
  if (t < 96)
    cap[(size_t)blockIdx.x * 96 + t] = redc[0][t] + redc[1][t] + redc[2][t] + redc[3][t];
}

// ---------------- merged camean2 + camlp ----------------
__global__ void camerge_kernel(const float* __restrict__ cap, const float* __restrict__ w1,
                               const float* __restrict__ b1, const float* __restrict__ w2,
                               const float* __restrict__ b2, float* __restrict__ avec) {
  __shared__ float red[4][192];
  __shared__ float means[192];
  int t = threadIdx.x;             // 768
  int q = t / 192, r = t % 192;
  int b = r / 96, c = r % 96;
  float s = 0.f;
  for (int j = 0; j < 32; ++j)
    s += cap[(size_t)(b * 128 + q * 32 + j) * 96 + c];
  red[q][r] = s;
  __syncthreads();
  if (t < 192)
    means[t] = (red[0][t] + red[1][t] + red[2][t] + red[3][t]) * (1.f / 4096.f);
  __syncthreads();
  if (t < 192) {
    int bb = t / 96, cc2 = t % 96;
    float tt[3];
    #pragma unroll
    for (int j = 0; j < 3; ++j) {
      float a = b1[j];
      for (int cc = 0; cc < 96; ++cc) a += means[bb * 96 + cc] * w1[j * 96 + cc];
      tt[j] = fmaxf(a, 0.f);
    }
    float a2 = b2[cc2];
    #pragma unroll
    for (int j = 0; j < 3; ++j) a2 += tt[j] * w2[cc2 * 3 + j];
    avec[t] = 1.f / (1.f + expf(-a2));
  }
}

// ---------------- merged weight prep ----------------
__global__ void wprep_all_kernel(const float* __restrict__ xpw, float4* __restrict__ xpwT,
                                 const float* __restrict__ cw, const float* __restrict__ mg3,
                                 const float* __restrict__ mg5, float* __restrict__ WC3T,
                                 float* __restrict__ W3T, float* __restrict__ W5T,
                                 const float* __restrict__ ipw, float4* __restrict__ WIPT,
                                 const float* __restrict__ mgiw, float4* __restrict__ WMGT,
                                 const float* __restrict__ opw, float4* __restrict__ WOPT,
                                 const float* __restrict__ mgow, float4* __restrict__ WMOT,
                                 const float* __restrict__ f1w, float4* __restrict__ WF1T,
                                 const float* __restrict__ f2w, float4* __restrict__ WF2T) {
  int idx = blockIdx.x * 256 + threadIdx.x;
  if (idx < 9216) {
    int k = idx / (48 * 48);
    int r = idx % (48 * 48);
    int j4 = r / 48, c = r % 48;
    float4 v = make_float4(0.f, 0.f, 0.f, 0.f);
    if (c < 38) v = ((const float4*)xpw)[((size_t)k * 38 + c) * 48 + j4];
    xpwT[((size_t)k * 48 + j4) * 48 + c] = v;
  }
  if (idx < 1728) { int c = idx / 9, j = idx % 9; WC3T[j * 192 + c] = cw[idx]; }
  if (idx < 2592) { int c = idx / 9, j = idx % 9; W3T[j * 288 + c] = mg3[idx]; }
  if (idx < 2400) { int c = idx / 25, j = idx % 25; W5T[j * 96 + c] = mg5[idx]; }
  if (idx < 9216) { int oc = idx % 384, j4 = idx / 384; WIPT[idx] = ((const float4*)ipw)[(size_t)oc * 24 + j4]; }
  if (idx < 9216) { int oc = idx % 384, j4 = idx / 384; WMGT[idx] = ((const float4*)mgiw)[(size_t)oc * 24 + j4]; }
  if (idx < 4608) { int oc = idx % 96, j4 = idx / 96; WOPT[idx] = ((const float4*)opw)[(size_t)oc * 48 + j4]; }
  if (idx < 4608) { int oc = idx % 96, j4 = idx / 96; WMOT[idx] = ((const float4*)mgow)[(size_t)oc * 48 + j4]; }
  if (idx < 1152) { int oc = idx % 48, j4 = idx / 48; WF1T[idx] = ((const float4*)f1w)[(size_t)oc * 24 + j4]; }
  if (idx < 1152) { int oc = idx % 96, j4 = idx / 96; WF2T[idx] = ((const float4*)f2w)[(size_t)oc * 12 + j4]; }
}

// ---------------- depthwise 3x3 + bias + silu (float4 channels) -> XC, XCT ----------------
__global__ void dwconv3_silu_kernel(const float* __restrict__ xx, const float* __restrict__ wc3t,
                                    const float* __restrict__ bias, float* __restrict__ xc,
                                    float* __restrict__ xct) {
  int idx = blockIdx.x * 256 + threadIdx.x;
  int d4 = idx % 48;
  int p = (idx / 48) & (Ll - 1);
  int b = idx / (48 * Ll);
  int h = p >> 6, wq = p & 63;
  const float4* base = (const float4*)xx + (size_t)b * Ll * 48;
  const float4* wt = (const float4*)wc3t;
  float4 bv = ((const float4*)bias)[d4];
  float a0 = bv.x, a1 = bv.y, a2 = bv.z, a3 = bv.w;
  #pragma unroll
  for (int i = 0; i < 3; ++i) {
    int hh = h - 1 + i;
    if ((unsigned)hh >= 64u) continue;
    #pragma unroll
    for (int j = 0; j < 3; ++j) {
      int ww2 = wq - 1 + j;
      if ((unsigned)ww2 >= 64u) continue;
      float4 x = base[(size_t)(hh * 64 + ww2) * 48 + d4];
      float4 w4 = wt[(i * 3 + j) * 48 + d4];
      a0 += x.x * w4.x; a1 += x.y * w4.y; a2 += x.z * w4.z; a3 += x.w * w4.w;
    }
  }
  float4 v = make_float4(silu_(a0), silu_(a1), silu_(a2), silu_(a3));
  ((float4*)xc)[idx] = v;
  int pt = (wq << 6) | h;
  ((float4*)xct)[((size_t)b * Ll + pt) * 48 + d4] = v;
}

// ---------------- x_proj ----------------
__global__ void proj_kernel(const float* __restrict__ xc, const float4* __restrict__ xpwT,
                            float* __restrict__ BSo, float* __restrict__ CSo,
                            float* __restrict__ DTS) {
  __shared__ float4 xv[32 * 49];
  int t = threadIdx.x;
  int pb = blockIdx.x & 127;
  int k = (blockIdx.x >> 7) & 3;
  int b = blockIdx.x >> 9;
  int bk = b * 4 + k;
  int pbase = pb * 32;
  for (int idx = t; idx < 32 * 48; idx += 256) {
    int it = idx / 48, j4 = idx - it * 48;
    xv[it * 49 + j4] = ((const float4*)xc)[((size_t)b * Ll + pbase + it) * 48 + j4];
  }
  __syncthreads();
  int g = t >> 4, ci = t & 15;
  float acc[2][3];
  #pragma unroll
  for (int p = 0; p < 2; ++p)
    #pragma unroll
    for (int cc = 0; cc < 3; ++cc) acc[p][cc] = 0.f;
  #pragma unroll 2
  for (int j4 = 0; j4 < 48; ++j4) {
    float4 xr0 = xv[g * 49 + j4];
    float4 xr1 = xv[(g + 16) * 49 + j4];
    const float4* wrow = xpwT + ((size_t)k * 48 + j4) * 48;
    #pragma unroll
    for (int cc = 0; cc < 3; ++cc) {
      float4 w4 = wrow[ci + 16 * cc];
      acc[0][cc] += xr0.x * w4.x + xr0.y * w4.y + xr0.z * w4.z + xr0.w * w4.w;
      acc[1][cc] += xr1.x * w4.x + xr1.y * w4.y + xr1.z * w4.z + xr1.w * w4.w;
    }
  }
  #pragma unroll
  for (int pI = 0; pI < 2; ++pI) {
    int p = pbase + g + 16 * pI;
    int pt = ((p & 63) << 6) | (p >> 6);
    int l = (k == 0) ? p : (k == 1) ? pt : (k == 2) ? (4095 - p) : (4095 - pt);
    #pragma unroll
    for (int cc = 0; cc < 3; ++cc) {
      int c = ci + 16 * cc;
      float v = acc[pI][cc];
      if (c < 6) DTS[((size_t)bk * 6 + c) * Ll + l] = v;
      else if (c < 22) BSo[((size_t)bk * Ll + l) * Nn + (c - 6)] = v;
      else if (c < 38) CSo[((size_t)bk * Ll + l) * Nn + (c - 22)] = v;
    }
  }
}

// ---------------- dt_proj + softplus -> pixel-major DT ----------------
__global__ void dtproj_kernel(const float* __restrict__ dts, const float* __restrict__ dtw,
                              const float* __restrict__ dtb, float* __restrict__ DTo) {
  __shared__ float sdts[6][64];
  int t = threadIdx.x;
  int lb = (blockIdx.x & 63) * 64;
  int bk = blockIdx.x >> 6;
  int k = bk & 3;
  if (t < 384) {
    int r = t / 64, l = t & 63;
    sdts[r][l] = dts[((size_t)bk * 6 + r) * Ll + lb + l];
  }
  __syncthreads();
  int d = t;
  const float* wr = dtw + ((size_t)k * DI + d) * Rr;
  float w0 = wr[0], w1 = wr[1], w2 = wr[2], w3 = wr[3], w4 = wr[4], w5 = wr[5];
  float b0 = dtb[k * DI + d];
  float* ob = DTo + ((size_t)bk * Ll + lb) * DI + d;
  #pragma unroll 4
  for (int l = 0; l < 64; ++l) {
    float a = b0 + sdts[0][l] * w0 + sdts[1][l] * w1 + sdts[2][l] * w2
            + sdts[3][l] * w3 + sdts[4][l] * w4 + sdts[5][l] * w5;
    float sp = (a > 20.f) ? a : log1pf(__expf(a));
    ob[(size_t)l * DI] = sp;
  }
}

// ---------------- scan pass A: 8-deep register prefetch, launch_bounds(256,3) ----------------
__global__ void __launch_bounds__(256, 3) scanA_kernel(
    const float* __restrict__ dtg, const float* __restrict__ xc,
    const float* __restrict__ xct, const float* __restrict__ bsg,
    const float* __restrict__ alog, float* __restrict__ P, float* __restrict__ Q) {
  int g = blockIdx.x * 256 + threadIdx.x;
  int ng = g & 3;
  int t1 = g >> 2;
  int d = t1 % DI;
  int t2 = t1 / DI;
  int c = t2 & 63;
  int bk = t2 >> 6;
  int k = bk & 3, b = bk >> 2;
  float4 al = ((const float4*)alog)[(size_t)(k * DI + d) * 4 + ng];
  float An0 = -__expf(al.x), An1 = -__expf(al.y), An2 = -__expf(al.z), An3 = -__expf(al.w);
  const float* dtp = dtg + ((size_t)bk * Ll + c * 64) * DI + d;
  const float4* bsp = (const float4*)bsg + ((size_t)bk * Ll + c * 64) * 4 + ng;
  const float* usrc = (k & 1) ? xct : xc;
  int p0 = (k >= 2) ? (4095 - c * 64) : (c * 64);
  int ustep = (k >= 2) ? -DI : DI;
  const float* up = usrc + ((size_t)b * Ll + p0) * DI + d;
  float P0 = 1.f, P1 = 1.f, P2 = 1.f, P3 = 1.f;
  float Q0 = 0.f, Q1 = 0.f, Q2 = 0.f, Q3 = 0.f;
  float dpre[8], upre[8];
  float4 bpre[8];
  #pragma unroll
  for (int i = 0; i < 8; ++i) {
    dpre[i] = dtp[(size_t)i * DI];
    upre[i] = up[(ptrdiff_t)i * ustep];
    bpre[i] = bsp[(size_t)i * 4];
  }
  for (int tg = 0; tg < 64; tg += 8) {
    #pragma unroll
    for (int i = 0; i < 8; ++i) {
      float dtv = dpre[i], u = upre[i];
      float4 Bv = bpre[i];
      int tn = tg + 8 + i;  // tail overrun: in-ws garbage, unused
      dpre[i] = dtp[(size_t)tn * DI];
      upre[i] = up[(ptrdiff_t)tn * ustep];
      bpre[i] = bsp[(size_t)tn * 4];
      float s = dtv * u;
      float a0 = __expf(dtv * An0), a1 = __expf(dtv * An1);
      float a2 = __expf(dtv * An2), a3 = __expf(dtv * An3);
      P0 *= a0; P1 *= a1; P2 *= a2; P3 *= a3;
      Q0 = Q0 * a0 + s * Bv.x; Q1 = Q1 * a1 + s * Bv.y;
      Q2 = Q2 * a2 + s * Bv.z; Q3 = Q3 * a3 + s * Bv.w;
    }
  }
  ((float4*)P)[g] = make_float4(P0, P1, P2, P3);
  ((float4*)Q)[g] = make_float4(Q0, Q1, Q2, Q3);
}

// ---------------- scan pass B ----------------
__global__ void scanB_kernel(const float* __restrict__ P, const float* __restrict__ Q,
                             float* __restrict__ H0) {
  int g = blockIdx.x * 256 + threadIdx.x;
  int n = g & 15;
  int d = (g >> 4) % DI;
  int bk = (g >> 4) / DI;
  size_t base = (size_t)bk * NC * DI * Nn + (size_t)d * Nn + n;
  float Ppre[4], Qpre[4];
  #pragma unroll
  for (int i = 0; i < 4; ++i) {
    Ppre[i] = P[base + (size_t)i * 3072];
    Qpre[i] = Q[base + (size_t)i * 3072];
  }
  float h = 0.f;
  for (int cg = 0; cg < 64; cg += 4) {
    #pragma unroll
    for (int i = 0; i < 4; ++i) {
      float pv = Ppre[i], qv = Qpre[i];
      Ppre[i] = P[base + (size_t)(cg + 4 + i) * 3072];
      Qpre[i] = Q[base + (size_t)(cg + 4 + i) * 3072];
      H0[base + (size_t)(cg + i) * 3072] = h;
      h = pv * h + qv;
    }
  }
}

// ---------------- scan pass C: 8-deep register prefetch, launch_bounds(256,3) ----------------
__global__ void __launch_bounds__(256, 3) scanC_kernel(
    const float* __restrict__ dtg, const float* __restrict__ xc,
    const float* __restrict__ xct, const float* __restrict__ bsg,
    const float* __restrict__ csg, const float* __restrict__ alog,
    const float* __restrict__ Dsv_, const float* __restrict__ H0,
    float* __restrict__ outy) {
  int g = blockIdx.x * 256 + threadIdx.x;
  int ng = g & 3;
  int t1 = g >> 2;
  int d = t1 % DI;
  int t2 = t1 / DI;
  int c = t2 & 63;
  int bk = t2 >> 6;
  int k = bk & 3, b = bk >> 2;
  float4 al = ((const float4*)alog)[(size_t)(k * DI + d) * 4 + ng];
  float An0 = -__expf(al.x), An1 = -__expf(al.y), An2 = -__expf(al.z), An3 = -__expf(al.w);
  float Dsv = Dsv_[k * DI + d];
  const float* dtp = dtg + ((size_t)bk * Ll + c * 64) * DI + d;
  const float4* bsp = (const float4*)bsg + ((size_t)bk * Ll + c * 64) * 4 + ng;
  const float4* csp = (const float4*)csg + ((size_t)bk * Ll + c * 64) * 4 + ng;
  const float* usrc = (k & 1) ? xct : xc;
  int p0 = (k >= 2) ? (4095 - c * 64) : (c * 64);
  int ustep = (k >= 2) ? -DI : DI;
  const float* up = usrc + ((size_t)b * Ll + p0) * DI + d;
  float* yo = outy + ((size_t)bk * Ll + c * 64) * DI + d;
  float4 h4 = ((const float4*)H0)[g];
  float h0 = h4.x, h1 = h4.y, h2 = h4.z, h3 = h4.w;
  float dpre[8], upre[8];
  float4 bpre[8], cpre[8];
  #pragma unroll
  for (int i = 0; i < 8; ++i) {
    dpre[i] = dtp[(size_t)i * DI];
    upre[i] = up[(ptrdiff_t)i * ustep];
    bpre[i] = bsp[(size_t)i * 4];
    cpre[i] = csp[(size_t)i * 4];
  }
  for (int tg = 0; tg < 64; tg += 8) {
    #pragma unroll
    for (int i = 0; i < 8; ++i) {
      float dtv = dpre[i], u = upre[i];
      float4 Bv = bpre[i], Cv = cpre[i];
      int tn = tg + 8 + i;  // tail overrun: in-ws garbage, unused
      dpre[i] = dtp[(size_t)tn * DI];
      upre[i] = up[(ptrdiff_t)tn * ustep];
      bpre[i] = bsp[(size_t)tn * 4];
      cpre[i] = csp[(size_t)tn * 4];
      float s = dtv * u;
      float a0 = __expf(dtv * An0), a1 = __expf(dtv * An1);
      float a2 = __expf(dtv * An2), a3 = __expf(dtv * An3);
      h0 = h0 * a0 + s * Bv.x; h1 = h1 * a1 + s * Bv.y;
      h2 = h2 * a2 + s * Bv.z; h3 = h3 * a3 + s * Bv.w;
      float yp = h0 * Cv.x + h1 * Cv.y + h2 * Cv.z + h3 * Cv.w;
      yp = qadd1(yp);
      yp = qadd2(yp);
      if (ng == 0) yo[(size_t)(tg + i) * DI] = yp + u * Dsv;
    }
  }
}

// ---------------- FFT branch (transposed intermediates) ----------------
__global__ void dft_row_kernel(const float* __restrict__ xf, float* __restrict__ Tr,
                               float* __restrict__ Ti) {
  __shared__ float row[4][64];
  __shared__ float cs[64], sn[64];
  int t = threadIdx.x, lane = t & 63, wv = t >> 6;
  int bch = blockIdx.x * 4 + wv;
  int h = bch & 63, bc = bch >> 6;
  row[wv][lane] = xf[(size_t)bch * 64 + lane];
  if (t < 64) {
    float ang = (float)t * 0.09817477042468103f;
    float s0, c0; sincosf(ang, &s0, &c0); sn[t] = s0; cs[t] = c0;
  }
  __syncthreads();
  if (lane < 33) {
    float ar = 0.f, ai = 0.f;
    for (int wq = 0; wq < 64; ++wq) {
      int j = (lane * wq) & 63;
      ar += row[wv][wq] * cs[j];
      ai -= row[wv][wq] * sn[j];
    }
    Tr[((size_t)bc * 33 + lane) * 64 + h] = ar;
    Ti[((size_t)bc * 33 + lane) * 64 + h] = ai;
  }
}

__global__ void dft_col_kernel(const float* __restrict__ Tr, const float* __restrict__ Ti,
                               float* __restrict__ Gr, float* __restrict__ Gi) {
  __shared__ float tr[4][64], ti[4][64];
  __shared__ float cs[64], sn[64];
  int t = threadIdx.x, lane = t & 63, wv = t >> 6;
  int idx = blockIdx.x * 4 + wv;
  int v = idx % 33, bc = idx / 33;
  tr[wv][lane] = Tr[((size_t)bc * 33 + v) * 64 + lane];
  ti[wv][lane] = Ti[((size_t)bc * 33 + v) * 64 + lane];
  if (t < 64) {
    float ang = (float)t * 0.09817477042468103f;
    float s0, c0; sincosf(ang, &s0, &c0); sn[t] = s0; cs[t] = c0;
  }
  __syncthreads();
  float ar = 0.f, ai = 0.f;
  for (int hh = 0; hh < 64; ++hh) {
    int j = (lane * hh) & 63;
    ar += tr[wv][hh] * cs[j] + ti[wv][hh] * sn[j];
    ai += ti[wv][hh] * cs[j] - tr[wv][hh] * sn[j];
  }
  Gr[((size_t)bc * 64 + lane) * 33 + v] = ar * (1.f / 64.f);
  Gi[((size_t)bc * 64 + lane) * 33 + v] = ai * (1.f / 64.f);
}

__global__ void fmix2_kernel(const float* __restrict__ Gr, const float* __restrict__ Gi,
                             const float* __restrict__ w, const float* __restrict__ bias,
                             float* __restrict__ Mr, float* __restrict__ Mi) {
  __shared__ float xs[16][100];
  int t = threadIdx.x;
  int uvb = (blockIdx.x % 132) * 16;
  int b = blockIdx.x / 132;
  for (int idx = t; idx < 96 * 16; idx += 256) {
    int ch = idx >> 4, px = idx & 15;
    const float* src = (ch & 1) ? Gi : Gr;
    xs[px][ch] = src[((size_t)(b * 48 + (ch >> 1))) * 2112 + uvb + px];
  }
  __syncthreads();
  int px = t >> 4, ci = t & 15;
  float acc[6];
  #pragma unroll
  for (int cc = 0; cc < 6; ++cc) acc[cc] = bias[ci + 16 * cc];
  const float4* xr4 = (const float4*)&xs[px][0];
  #pragma unroll 2
  for (int j4 = 0; j4 < 24; ++j4) {
    float4 x4 = xr4[j4];
    #pragma unroll
    for (int cc = 0; cc < 6; ++cc) {
      float4 w4 = ((const float4*)w)[(size_t)(ci + 16 * cc) * 24 + j4];
      acc[cc] += x4.x * w4.x + x4.y * w4.y + x4.z * w4.z + x4.w * w4.w;
    }
  }
  int uv = uvb + px;
  int u = uv / 33, vv2 = uv % 33;
  #pragma unroll
  for (int cc = 0; cc < 6; ++cc) {
    int o = ci + 16 * cc;
    float v = silu_(acc[cc]);
    float* dst = (o & 1) ? Mi : Mr;
    dst[((size_t)(b * 48 + (o >> 1))) * 2112 + vv2 * 64 + u] = v;
  }
}

__global__ void idft_col_kernel(const float* __restrict__ Mr, const float* __restrict__ Mi,
                                float* __restrict__ gr, float* __restrict__ gi) {
  __shared__ float mr[4][64], mi[4][64];
  __shared__ float cs[64], sn[64];
  int t = threadIdx.x, lane = t & 63, wv = t >> 6;
  int idx = blockIdx.x * 4 + wv;
  int v = idx % 33, bc = idx / 33;
  mr[wv][lane] = Mr[((size_t)bc * 33 + v) * 64 + lane];
  mi[wv][lane] = Mi[((size_t)bc * 33 + v) * 64 + lane];
  if (t < 64) {
    float ang = (float)t * 0.09817477042468103f;
    float s0, c0; sincosf(ang, &s0, &c0); sn[t] = s0; cs[t] = c0;
  }
  __syncthreads();
  float ar = 0.f, ai = 0.f;
  for (int u = 0; u < 64; ++u) {
    int j = (lane * u) & 63;
    ar += mr[wv][u] * cs[j] - mi[wv][u] * sn[j];
    ai += mr[wv][u] * sn[j] + mi[wv][u] * cs[j];
  }
  gr[((size_t)bc * 64 + lane) * 33 + v] = ar;
  gi[((size_t)bc * 64 + lane) * 33 + v] = ai;
}

__global__ void irfft_row_kernel(const float* __restrict__ gr, const float* __restrict__ gi,
                                 float* __restrict__ ysp) {
  __shared__ float r[4][33], im[4][33];
  __shared__ float cs[64], sn[64];
  int t = threadIdx.x, lane = t & 63, wv = t >> 6;
  int bch = blockIdx.x * 4 + wv;
  if (lane < 33) {
    r[wv][lane] = gr[(size_t)bch * 33 + lane];
    im[wv][lane] = gi[(size_t)bch * 33 + lane];
  }
  if (t < 64) {
    float ang = (float)t * 0.09817477042468103f;
    float s0, c0; sincosf(ang, &s0, &c0); sn[t] = s0; cs[t] = c0;
  }
  __syncthreads();
  float acc = r[wv][0] + ((lane & 1) ? -r[wv][32] : r[wv][32]);
  for (int v = 1; v < 32; ++v) {
    int j = (v * lane) & 63;
    acc += 2.f * (r[wv][v] * cs[j] - im[wv][v] * sn[j]);
  }
  ysp[(size_t)bch * 64 + lane] = acc * (1.f / 64.f);
}

// ---------------- MGCB depthwise + gelu gate (float4 channels) ----------------
__global__ void mgcb_dw_kernel(const float* __restrict__ pm, const float* __restrict__ w3t,
                               const float* __restrict__ w5t, float* __restrict__ ymg) {
  int idx = blockIdx.x * 256 + threadIdx.x;
  int c4 = idx % 48;
  int p = (idx / 48) & (Ll - 1);
  int b = idx / (48 * Ll);
  int h = p >> 6, wq = p & 63;
  const float4* base = (const float4*)pm + (size_t)b * Ll * 96;
  const float4* wt3 = (const float4*)w3t;
  float g0 = 0.f, g1 = 0.f, g2 = 0.f, g3 = 0.f;
  float m0 = 0.f, m1 = 0.f, m2 = 0.f, m3 = 0.f;
  if (c4 < 24) {
    #pragma unroll
    for (int i = 0; i < 3; ++i) {
      int hh = h - 1 + i; if ((unsigned)hh >= 64u) continue;
      #pragma unroll
      for (int j = 0; j < 3; ++j) {
        int ww2 = wq - 1 + j; if ((unsigned)ww2 >= 64u) continue;
        const float4* px = base + (size_t)(hh * 64 + ww2) * 96;
        float4 xg = px[c4];
        float4 wg = wt3[(i * 3 + j) * 72 + c4];
        g0 += xg.x * wg.x; g1 += xg.y * wg.y; g2 += xg.z * wg.z; g3 += xg.w * wg.w;
        float4 xm = px[48 + c4];
        float4 wm = wt3[(i * 3 + j) * 72 + 48 + c4];
        m0 += xm.x * wm.x; m1 += xm.y * wm.y; m2 += xm.z * wm.z; m3 += xm.w * wm.w;
      }
    }
  } else {
    #pragma unroll
    for (int i = 0; i < 3; ++i) {
      int hh = h - 1 + i; if ((unsigned)hh >= 64u) continue;
      #pragma unroll
      for (int j = 0; j < 3; ++j) {
        int ww2 = wq - 1 + j; if ((unsigned)ww2 >= 64u) continue;
        float4 xg = base[(size_t)(hh * 64 + ww2) * 96 + c4];
        float4 wg = wt3[(i * 3 + j) * 72 + c4];
        g0 += xg.x * wg.x; g1 += xg.y * wg.y; g2 += xg.z * wg.z; g3 += xg.w * wg.w;
      }
    }
    const float4* wt5 = (const float4*)w5t;
    int cw4 = c4 - 24;
    #pragma unroll
    for (int i = 0; i < 5; ++i) {
      int hh = h - 2 + i; if ((unsigned)hh >= 64u) continue;
      #pragma unroll
      for (int j = 0; j < 5; ++j) {
        int ww2 = wq - 2 + j; if ((unsigned)ww2 >= 64u) continue;
        float4 xm = base[(size_t)(hh * 64 + ww2) * 96 + 48 + c4];
        float4 wm = wt5[(i * 5 + j) * 24 + cw4];
        m0 += xm.x * wm.x; m1 += xm.y * wm.y; m2 += xm.z * wm.z; m3 += xm.w * wm.w;
      }
    }
  }
  const float IS2 = 0.70710678118654752f;
  float4 o;
  o.x = 0.5f * g0 * (1.f + erff(g0 * IS2)) * m0;
  o.y = 0.5f * g1 * (1.f + erff(g1 * IS2)) * m1;
  o.z = 0.5f * g2 * (1.f + erff(g2 * IS2)) * m2;
  o.w = 0.5f * g3 * (1.f + erff(g3 * IS2)) * m3;
  ((float4*)ymg)[idx] = o;
}

// ---------------- final (float4) ----------------
__global__ void final_kernel(const float* __restrict__ xres, const float* __restrict__ yc,
                             const float* __restrict__ ss2, const float* __restrict__ avec,
                             float* __restrict__ out) {
  int i4 = blockIdx.x * 256 + threadIdx.x;   // 196608 float4
  int e0 = i4 * 4;
  int c = e0 % 96;
  int b = e0 / (Ll * 96);
  float4 xr = ((const float4*)xres)[i4];
  float4 yv = ((const float4*)yc)[i4];
  const float* av = avec + b * 96 + c;
  const float* sv = ss2 + c;
  float4 o;
  o.x = xr.x * sv[0] + yv.x * av[0];
  o.y = xr.y * sv[1] + yv.y * av[1];
  o.z = xr.z * sv[2] + yv.z * av[2];
  o.w = xr.w * sv[3] + yv.w * av[3];
  ((float4*)out)[i4] = o;
}

// ---------------- host ----------------
extern "C" void kernel_launch(void* const* d_in, const int* in_sizes, int n_in,
                              void* d_out, int out_size, void* d_ws, size_t ws_size,
                              hipStream_t stream) {
  const float* input      = (const float*)d_in[0];
  const float* ln1_g      = (const float*)d_in[1];
  const float* ln1_b      = (const float*)d_in[2];
  const float* skip_scale = (const float*)d_in[3];
  const float* skip_scale2= (const float*)d_in[4];
  const float* ln2_g      = (const float*)d_in[5];
  const float* ln2_b      = (const float*)d_in[6];
  const float* in_proj_w  = (const float*)d_in[7];
  const float* conv2d_w   = (const float*)d_in[8];
  const float* conv2d_b   = (const float*)d_in[9];
  const float* x_proj_w   = (const float*)d_in[10];
  const float* dt_proj_w  = (const float*)d_in[11];
  const float* dt_proj_b  = (const float*)d_in[12];
  const float* A_logs     = (const float*)d_in[13];
  const float* Ds         = (const float*)d_in[14];
  const float* out_norm_g = (const float*)d_in[15];
  const float* out_norm_b = (const float*)d_in[16];
  const float* out_proj_w = (const float*)d_in[17];
  const float* f1_w       = (const float*)d_in[18];
  const float* f1_b       = (const float*)d_in[19];
  const float* fm_w       = (const float*)d_in[20];
  const float* fm_b       = (const float*)d_in[21];
  const float* f2_w       = (const float*)d_in[22];
  const float* f2_b       = (const float*)d_in[23];
  const float* mg_in_w    = (const float*)d_in[24];
  const float* mg_dw3_w   = (const float*)d_in[25];
  const float* mg_dw5_w   = (const float*)d_in[26];
  const float* mg_out_w   = (const float*)d_in[27];
  const float* ca_w1      = (const float*)d_in[28];
  const float* ca_b1      = (const float*)d_in[29];
  const float* ca_w2      = (const float*)d_in[30];
  const float* ca_b2      = (const float*)d_in[31];

  float* W = (float*)d_ws;
  float* XN    = W;                     // 786432 (spare)
  float* ZSILU = XN + 786432;           // 1572864
  float* XX    = ZSILU + 1572864;       // 1572864
  float* XC    = XX + 1572864;          // 1572864
  float* XCT   = XC + 1572864;          // 1572864
  float* DT    = XCT + 1572864;         // 6291456
  float* BSb   = DT + 6291456;          // 524288
  float* CSb   = BSb + 524288;          // 524288
  float* PP    = CSb + 524288;          // 1572864
  float* QQ    = PP + 1572864;          // 1572864
  float* H0    = QQ + 1572864;          // 1572864
  float* OUTY  = H0 + 1572864;          // 6291456
  float* YGATE = OUTY + 6291456;        // 1572864 (spare)
  float* ATTN  = YGATE + 1572864;       // 786432 (spare)
  float* FFTOUT= ATTN + 786432;         // 786432
  float* XRES  = FFTOUT + 786432;       // 786432
  float* XN2   = XRES + 786432;         // 786432
  float* MEANS = XN2 + 786432;          // 192 (spare)
  float* AVEC  = MEANS + 192;           // 192
  float* XPWT  = AVEC + 192;            // 36864
  float* WC3T  = XPWT + 36864;          // 1728
  float* W3T   = WC3T + 1728;           // 2592
  float* W5T   = W3T + 2592;            // 2400
  float* CAP   = W5T + 2400;            // 24576
  float* WIPT  = CAP + 24576;           // 36864
  float* WMGT  = WIPT + 36864;          // 36864
  float* WOPT  = WMGT + 36864;          // 18432
  float* WMOT  = WOPT + 18432;          // 18432
  float* WF1T  = WMOT + 18432;          // 4608
  float* WF2T  = WF1T + 4608;           // 4608
  float* DTS = H0;
  float* XF  = PP;                      // 393216
  float* TR  = XF + 393216;
  float* TI  = TR + 202752;
  float* GR  = TI + 202752;
  float* GI  = GR + 202752;
  float* MR  = TR;
  float* MI  = TI;
  float* G2R = GR;
  float* G2I = GI;
  float* YSP = GI + 202752;
  float* PMG = DT;
  float* YMG = DT + 3145728;
  float* YCb = YMG + 1572864;

  wprep_all_kernel<<<36, 256, 0, stream>>>(
      x_proj_w, (float4*)XPWT, conv2d_w, mg_dw3_w, mg_dw5_w, WC3T, W3T, W5T,
      in_proj_w, (float4*)WIPT, mg_in_w, (float4*)WMGT, out_proj_w, (float4*)WOPT,
      mg_out_w, (float4*)WMOT, f1_w, (float4*)WF1T, f2_w, (float4*)WF2T);
  conv1x1v2_kernel<96, 384, 96, 64, 0, 2, 0, 0, 1><<<512, 256, 0, stream>>>(
      input, (const float4*)WIPT, nullptr, XX, ZSILU, ln1_g, ln1_b);
  dwconv3_silu_kernel<<<1536, 256, 0, stream>>>(XX, WC3T, conv2d_b, XC, XCT);
  proj_kernel<<<1024, 256, 0, stream>>>(XC, (const float4*)XPWT, BSb, CSb, DTS);
  dtproj_kernel<<<512, 192, 0, stream>>>(DTS, dt_proj_w, dt_proj_b, DT);
  scanA_kernel<<<1536, 256, 0, stream>>>(DT, XC, XCT, BSb, A_logs, PP, QQ);
  scanB_kernel<<<96, 256, 0, stream>>>(PP, QQ, H0);
  conv1x1v2_kernel<96, 48, 48, 32, 0, 1, 1, 1, 1><<<256, 256, 0, stream>>>(
      input, (const float4*)WF1T, f1_b, XF, nullptr, ln1_g, ln1_b);
  dft_row_kernel<<<1536, 256, 0, stream>>>(XF, TR, TI);
  dft_col_kernel<<<792, 256, 0, stream>>>(TR, TI, GR, GI);
  fmix2_kernel<<<264, 256, 0, stream>>>(GR, GI, fm_w, fm_b, MR, MI);
  idft_col_kernel<<<792, 256, 0, stream>>>(MR, MI, G2R, G2I);
  irfft_row_kernel<<<1536, 256, 0, stream>>>(G2R, G2I, YSP);
  conv1x1v2_kernel<48, 96, 96, 32, 1, 0, 0, 1, 0><<<256, 256, 0, stream>>>(
      YSP, (const float4*)WF2T, f2_b, FFTOUT, nullptr, nullptr, nullptr);
  scanC_kernel<<<1536, 256, 0, stream>>>(DT, XC, XCT, BSb, CSb, A_logs, Ds, H0, OUTY);
  outproj_fused_kernel<<<256, 256, 0, stream>>>(
      OUTY, ZSILU, out_norm_g, out_norm_b, (const float4*)WOPT, input, FFTOUT,
      skip_scale, ln2_g, ln2_b, XRES, XN2);
  conv1x1v2_kernel<96, 384, 96, 64, 0, 0, 0, 0, 0><<<512, 256, 0, stream>>>(
      XN2, (const float4*)WMGT, nullptr, PMG, nullptr, nullptr, nullptr);
  mgcb_dw_kernel<<<1536, 256, 0, stream>>>(PMG, W3T, W5T, YMG);
  mgout_fused_kernel<<<256, 256, 0, stream>>>(YMG, (const float4*)WMOT, YCb, CAP);
  camerge_kernel<<<1, 768, 0, stream>>>(CAP, ca_w1, ca_b1, ca_w2, ca_b2, AVEC);
  final_kernel<<<768, 256, 0, stream>>>(XRES, YCb, skip_scale2, AVEC, (float*)d_out);
}

// Round 20
// 345.786 us; speedup vs baseline: 1.0217x; 1.0217x over previous
//
#include <hip/hip_runtime.h>
#include <math.h>

#define DEV __device__ __forceinline__

constexpr int DI = 192, Nn = 16, Rr = 6;
constexpr int Cc = 96;
constexpr int Ll = 4096;           // 64*64
constexpr int NC = 64;             // scan chunks of 64 steps

DEV float silu_(float x) { return x / (1.f + __expf(-x)); }
DEV float qadd1(float v) {
  int i = __builtin_amdgcn_mov_dpp(__float_as_int(v), 0xB1, 0xF, 0xF, true);
  return v + __int_as_float(i);
}
DEV float qadd2(float v) {
  int i = __builtin_amdgcn_mov_dpp(__float_as_int(v), 0x4E, 0xF, 0xF, true);
  return v + __int_as_float(i);
}

// ---------------- register-tiled 1x1 conv (fp32 micro-GEMM), TRANSPOSED weights [j4][oc] ----------------
template<int CIN, int COUT, int CB, int PXB, int IN_MODE, int OUT_MODE, int ACT, int HAS_BIAS, int LN>
__global__ void conv1x1v2_kernel(const float* __restrict__ in, const float4* __restrict__ wt,
                                 const float* __restrict__ bias, float* __restrict__ out,
                                 float* __restrict__ out2, const float* __restrict__ lng,
                                 const float* __restrict__ lnb) {
  constexpr int J4 = CIN / 4, STR = J4 + 1, CCN = CB / 16, PXT = PXB / 16;
  constexpr int NPB = 8192 / PXB;
  __shared__ float4 xv[PXB * STR];
  int t = threadIdx.x;
  int pb = blockIdx.x % NPB;
  int cbase = (blockIdx.x / NPB) * CB;
  int pbase = pb * PXB;
  if (IN_MODE == 0) {
    for (int idx = t; idx < PXB * J4; idx += 256) {
      int px = idx / J4, j4 = idx - px * J4;
      xv[px * STR + j4] = ((const float4*)in)[(size_t)(pbase + px) * J4 + j4];
    }
  } else {
    for (int idx = t; idx < PXB * CIN; idx += 256) {
      int px = idx & (PXB - 1), c = idx / PXB;
      int gp = pbase + px; int b = gp >> 12, p = gp & 4095;
      ((float*)xv)[px * (STR * 4) + c] = in[((size_t)b * CIN + c) * Ll + p];
    }
  }
  __syncthreads();
  if constexpr (LN) {
    constexpr int TPX = 256 / PXB;
    constexpr int CHUNK = CIN / TPX;
    int px = t / TPX, sub = t % TPX;
    float* row = (float*)(xv + px * STR);
    float sm = 0.f, sq = 0.f;
    #pragma unroll
    for (int j2 = 0; j2 < CHUNK; ++j2) {
      float v = row[sub + j2 * TPX];
      sm += v; sq += v * v;
    }
    #pragma unroll
    for (int m = 1; m < TPX; m <<= 1) {
      sm += __shfl_xor(sm, m, 64);
      sq += __shfl_xor(sq, m, 64);
    }
    float mean = sm * (1.f / CIN);
    float rs = rsqrtf(sq * (1.f / CIN) - mean * mean + 1e-6f);
    #pragma unroll
    for (int j2 = 0; j2 < CHUNK; ++j2) {
      int j = sub + j2 * TPX;
      row[j] = (row[j] - mean) * rs * lng[j] + lnb[j];
    }
    __syncthreads();
  }
  int g = t >> 4, ci = t & 15;
  float acc[PXT][CCN];
  #pragma unroll
  for (int cc = 0; cc < CCN; ++cc) {
    float b0 = HAS_BIAS ? bias[cbase + ci + 16 * cc] : 0.f;
    #pragma unroll
    for (int p = 0; p < PXT; ++p) acc[p][cc] = b0;
  }
  #pragma unroll 2
  for (int j4 = 0; j4 < J4; ++j4) {
    float4 xr[PXT];
    #pragma unroll
    for (int p = 0; p < PXT; ++p) xr[p] = xv[(g + 16 * p) * STR + j4];
    #pragma unroll
    for (int cc = 0; cc < CCN; ++cc) {
      float4 w4 = wt[(size_t)j4 * COUT + cbase + ci + 16 * cc];
      #pragma unroll
      for (int p = 0; p < PXT; ++p)
        acc[p][cc] += xr[p].x * w4.x + xr[p].y * w4.y + xr[p].z * w4.z + xr[p].w * w4.w;
    }
  }
  #pragma unroll
  for (int p = 0; p < PXT; ++p) {
    int gp = pbase + g + 16 * p;
    #pragma unroll
    for (int cc = 0; cc < CCN; ++cc) {
      int c = cbase + ci + 16 * cc;
      float v = acc[p][cc];
      if (OUT_MODE == 2) {
        if (c < 192) out[(size_t)gp * 192 + c] = v;
        else out2[(size_t)gp * 192 + (c - 192)] = silu_(v);
      } else {
        if (ACT == 1) v = silu_(v);
        if (OUT_MODE == 0) out[(size_t)gp * COUT + c] = v;
        else { int bb = gp >> 12, p2 = gp & 4095; out[((size_t)bb * COUT + c) * Ll + p2] = v; }
      }
    }
  }
}

// ---------------- FUSED attention tail: ycomb + out_proj + resln ----------------
__global__ void outproj_fused_kernel(
    const float* __restrict__ outy, const float* __restrict__ zs,
    const float* __restrict__ ong, const float* __restrict__ onb,
    const float4* __restrict__ wt, const float* __restrict__ input,
    const float* __restrict__ fftout, const float* __restrict__ ss,
    const float* __restrict__ ln2g, const float* __restrict__ ln2b,
    float* __restrict__ xres, float* __restrict__ xn2) {
  __shared__ float4 xv[32 * 49];
  int t = threadIdx.x;
  int pbase = blockIdx.x * 32;
  {
    int px = t >> 3, sub = t & 7;
    int pix = pbase + px;
    int p = pix & 4095, b = pix >> 12;
    int pt = ((p & 63) << 6) | (p >> 6);
    size_t base = (size_t)b * 4 * Ll * DI;
    const float* y0 = outy + base + (size_t)p * DI;
    const float* y1 = outy + base + ((size_t)Ll + pt) * DI;
    const float* y2 = outy + base + ((size_t)2 * Ll + (4095 - p)) * DI;
    const float* y3 = outy + base + ((size_t)3 * Ll + (4095 - pt)) * DI;
    float v[24];
    float sm = 0.f, sq = 0.f;
    #pragma unroll
    for (int j = 0; j < 24; ++j) {
      int c = sub + 8 * j;
      float vv = y0[c] + y1[c] + y2[c] + y3[c];
      v[j] = vv; sm += vv; sq += vv * vv;
    }
    #pragma unroll
    for (int m = 1; m < 8; m <<= 1) {
      sm += __shfl_xor(sm, m, 64);
      sq += __shfl_xor(sq, m, 64);
    }
    float mean = sm * (1.f / 192.f);
    float rs = rsqrtf(sq * (1.f / 192.f) - mean * mean + 1e-5f);
    const float* zrow = zs + (size_t)pix * DI;
    float* row = (float*)(xv + px * 49);
    #pragma unroll
    for (int j = 0; j < 24; ++j) {
      int c = sub + 8 * j;
      row[c] = ((v[j] - mean) * rs * ong[c] + onb[c]) * zrow[c];
    }
  }
  __syncthreads();
  int g = t >> 4, ci = t & 15;
  float acc[2][6];
  #pragma unroll
  for (int pI = 0; pI < 2; ++pI)
    #pragma unroll
    for (int cc = 0; cc < 6; ++cc) acc[pI][cc] = 0.f;
  #pragma unroll 2
  for (int j4 = 0; j4 < 48; ++j4) {
    float4 xr0 = xv[g * 49 + j4];
    float4 xr1 = xv[(g + 16) * 49 + j4];
    #pragma unroll
    for (int cc = 0; cc < 6; ++cc) {
      float4 w4 = wt[(size_t)j4 * 96 + ci + 16 * cc];
      acc[0][cc] += xr0.x * w4.x + xr0.y * w4.y + xr0.z * w4.z + xr0.w * w4.w;
      acc[1][cc] += xr1.x * w4.x + xr1.y * w4.y + xr1.z * w4.z + xr1.w * w4.w;
    }
  }
  #pragma unroll
  for (int pI = 0; pI < 2; ++pI) {
    int gp = pbase + g + 16 * pI;
    float vv[6];
    float sm = 0.f, sq = 0.f;
    #pragma unroll
    for (int cc = 0; cc < 6; ++cc) {
      int c = ci + 16 * cc;
      float x = input[(size_t)gp * Cc + c] * ss[c] + acc[pI][cc] + fftout[(size_t)gp * Cc + c];
      vv[cc] = x; sm += x; sq += x * x;
    }
    #pragma unroll
    for (int m = 1; m < 16; m <<= 1) {
      sm += __shfl_xor(sm, m, 64);
      sq += __shfl_xor(sq, m, 64);
    }
    float mean = sm * (1.f / 96.f);
    float rs = rsqrtf(sq * (1.f / 96.f) - mean * mean + 1e-5f);
    #pragma unroll
    for (int cc = 0; cc < 6; ++cc) {
      int c = ci + 16 * cc;
      xres[(size_t)gp * Cc + c] = vv[cc];
      xn2[(size_t)gp * Cc + c] = (vv[cc] - mean) * rs * ln2g[c] + ln2b[c];
    }
  }
}

// ---------------- mg_out conv + fused channel-partial sums ----------------
__global__ void mgout_fused_kernel(const float* __restrict__ in, const float4* __restrict__ wt,
                                   float* __restrict__ out, float* __restrict__ cap) {
  __shared__ float4 xv[32 * 49];
  __shared__ float redc[4][96];
  int t = threadIdx.x;
  int pbase = blockIdx.x * 32;
  for (int idx = t; idx < 32 * 48; idx += 256) {
    int px = idx / 48, j4 = idx - px * 48;
    xv[px * 49 + j4] = ((const float4*)in)[(size_t)(pbase + px) * 48 + j4];
  }
  __syncthreads();
  int g = t >> 4, ci = t & 15;
  float acc[2][6];
  #pragma unroll
  for (int pI = 0; pI < 2; ++pI)
    #pragma unroll
    for (int cc = 0; cc < 6; ++cc) acc[pI][cc] = 0.f;
  #pragma unroll 2
  for (int j4 = 0; j4 < 48; ++j4) {
    float4 xr0 = xv[g * 49 + j4];
    float4 xr1 = xv[(g + 16) * 49 + j4];
    #pragma unroll
    for (int cc = 0; cc < 6; ++cc) {
      float4 w4 = wt[(size_t)j4 * 96 + ci + 16 * cc];
      acc[0][cc] += xr0.x * w4.x + xr0.y * w4.y + xr0.z * w4.z + xr0.w * w4.w;
      acc[1][cc] += xr1.x * w4.x + xr1.y * w4.y + xr1.z * w4.z + xr1.w * w4.w;
    }
  }
  float ps[6];
  #pragma unroll
  for (int cc = 0; cc < 6; ++cc) ps[cc] = acc[0][cc] + acc[1][cc];
  #pragma unroll
  for (int pI = 0; pI < 2; ++pI) {
    int gp = pbase + g + 16 * pI;
    #pragma unroll
    for (int cc = 0; cc < 6; ++cc)
      out[(size_t)gp * 96 + ci + 16 * cc] = acc[pI][cc];
  }
  #pragma unroll
  for (int cc = 0; cc < 6; ++cc) {
    ps[cc] += __shfl_xor(ps[cc], 16, 64);
    ps[cc] += __shfl_xor(ps[cc], 32, 64);
  }
  if ((t & 63) < 16) {
    #pragma unroll
    for (int cc = 0; cc < 6; ++cc) redc[t >> 6][ci + 16 * cc] = ps[cc];
  }
  __syncthreads();
  if (t < 96)
    cap[(size_t)blockIdx.x * 96 + t] = redc[0][t] + redc[1][t] + redc[2][t] + redc[3][t];
}

// ---------------- merged camean2 + camlp ----------------
__global__ void camerge_kernel(const float* __restrict__ cap, const float* __restrict__ w1,
                               const float* __restrict__ b1, const float* __restrict__ w2,
                               const float* __restrict__ b2, float* __restrict__ avec) {
  __shared__ float red[4][192];
  __shared__ float means[192];
  int t = threadIdx.x;             // 768
  int q = t / 192, r = t % 192;
  int b = r / 96, c = r % 96;
  float s = 0.f;
  for (int j = 0; j < 32; ++j)
    s += cap[(size_t)(b * 128 + q * 32 + j) * 96 + c];
  red[q][r] = s;
  __syncthreads();
  if (t < 192)
    means[t] = (red[0][t] + red[1][t] + red[2][t] + red[3][t]) * (1.f / 4096.f);
  __syncthreads();
  if (t < 192) {
    int bb = t / 96, cc2 = t % 96;
    float tt[3];
    #pragma unroll
    for (int j = 0; j < 3; ++j) {
      float a = b1[j];
      for (int cc = 0; cc < 96; ++cc) a += means[bb * 96 + cc] * w1[j * 96 + cc];
      tt[j] = fmaxf(a, 0.f);
    }
    float a2 = b2[cc2];
    #pragma unroll
    for (int j = 0; j < 3; ++j) a2 += tt[j] * w2[cc2 * 3 + j];
    avec[t] = 1.f / (1.f + expf(-a2));
  }
}

// ---------------- merged weight prep ----------------
__global__ void wprep_all_kernel(const float* __restrict__ xpw, float4* __restrict__ xpwT,
                                 const float* __restrict__ cw, const float* __restrict__ mg3,
                                 const float* __restrict__ mg5, float* __restrict__ WC3T,
                                 float* __restrict__ W3T, float* __restrict__ W5T,
                                 const float* __restrict__ ipw, float4* __restrict__ WIPT,
                                 const float* __restrict__ mgiw, float4* __restrict__ WMGT,
                                 const float* __restrict__ opw, float4* __restrict__ WOPT,
                                 const float* __restrict__ mgow, float4* __restrict__ WMOT,
                                 const float* __restrict__ f1w, float4* __restrict__ WF1T,
                                 const float* __restrict__ f2w, float4* __restrict__ WF2T) {
  int idx = blockIdx.x * 256 + threadIdx.x;
  if (idx < 9216) {
    int k = idx / (48 * 48);
    int r = idx % (48 * 48);
    int j4 = r / 48, c = r % 48;
    float4 v = make_float4(0.f, 0.f, 0.f, 0.f);
    if (c < 38) v = ((const float4*)xpw)[((size_t)k * 38 + c) * 48 + j4];
    xpwT[((size_t)k * 48 + j4) * 48 + c] = v;
  }
  if (idx < 1728) { int c = idx / 9, j = idx % 9; WC3T[j * 192 + c] = cw[idx]; }
  if (idx < 2592) { int c = idx / 9, j = idx % 9; W3T[j * 288 + c] = mg3[idx]; }
  if (idx < 2400) { int c = idx / 25, j = idx % 25; W5T[j * 96 + c] = mg5[idx]; }
  if (idx < 9216) { int oc = idx % 384, j4 = idx / 384; WIPT[idx] = ((const float4*)ipw)[(size_t)oc * 24 + j4]; }
  if (idx < 9216) { int oc = idx % 384, j4 = idx / 384; WMGT[idx] = ((const float4*)mgiw)[(size_t)oc * 24 + j4]; }
  if (idx < 4608) { int oc = idx % 96, j4 = idx / 96; WOPT[idx] = ((const float4*)opw)[(size_t)oc * 48 + j4]; }
  if (idx < 4608) { int oc = idx % 96, j4 = idx / 96; WMOT[idx] = ((const float4*)mgow)[(size_t)oc * 48 + j4]; }
  if (idx < 1152) { int oc = idx % 48, j4 = idx / 48; WF1T[idx] = ((const float4*)f1w)[(size_t)oc * 24 + j4]; }
  if (idx < 1152) { int oc = idx % 96, j4 = idx / 96; WF2T[idx] = ((const float4*)f2w)[(size_t)oc * 12 + j4]; }
}

// ---------------- depthwise 3x3 + bias + silu (float4 channels) -> XC, XCT ----------------
__global__ void dwconv3_silu_kernel(const float* __restrict__ xx, const float* __restrict__ wc3t,
                                    const float* __restrict__ bias, float* __restrict__ xc,
                                    float* __restrict__ xct) {
  int idx = blockIdx.x * 256 + threadIdx.x;
  int d4 = idx % 48;
  int p = (idx / 48) & (Ll - 1);
  int b = idx / (48 * Ll);
  int h = p >> 6, wq = p & 63;
  const float4* base = (const float4*)xx + (size_t)b * Ll * 48;
  const float4* wt = (const float4*)wc3t;
  float4 bv = ((const float4*)bias)[d4];
  float a0 = bv.x, a1 = bv.y, a2 = bv.z, a3 = bv.w;
  #pragma unroll
  for (int i = 0; i < 3; ++i) {
    int hh = h - 1 + i;
    if ((unsigned)hh >= 64u) continue;
    #pragma unroll
    for (int j = 0; j < 3; ++j) {
      int ww2 = wq - 1 + j;
      if ((unsigned)ww2 >= 64u) continue;
      float4 x = base[(size_t)(hh * 64 + ww2) * 48 + d4];
      float4 w4 = wt[(i * 3 + j) * 48 + d4];
      a0 += x.x * w4.x; a1 += x.y * w4.y; a2 += x.z * w4.z; a3 += x.w * w4.w;
    }
  }
  float4 v = make_float4(silu_(a0), silu_(a1), silu_(a2), silu_(a3));
  ((float4*)xc)[idx] = v;
  int pt = (wq << 6) | h;
  ((float4*)xct)[((size_t)b * Ll + pt) * 48 + d4] = v;
}

// ---------------- x_proj ----------------
__global__ void proj_kernel(const float* __restrict__ xc, const float4* __restrict__ xpwT,
                            float* __restrict__ BSo, float* __restrict__ CSo,
                            float* __restrict__ DTS) {
  __shared__ float4 xv[32 * 49];
  int t = threadIdx.x;
  int pb = blockIdx.x & 127;
  int k = (blockIdx.x >> 7) & 3;
  int b = blockIdx.x >> 9;
  int bk = b * 4 + k;
  int pbase = pb * 32;
  for (int idx = t; idx < 32 * 48; idx += 256) {
    int it = idx / 48, j4 = idx - it * 48;
    xv[it * 49 + j4] = ((const float4*)xc)[((size_t)b * Ll + pbase + it) * 48 + j4];
  }
  __syncthreads();
  int g = t >> 4, ci = t & 15;
  float acc[2][3];
  #pragma unroll
  for (int p = 0; p < 2; ++p)
    #pragma unroll
    for (int cc = 0; cc < 3; ++cc) acc[p][cc] = 0.f;
  #pragma unroll 2
  for (int j4 = 0; j4 < 48; ++j4) {
    float4 xr0 = xv[g * 49 + j4];
    float4 xr1 = xv[(g + 16) * 49 + j4];
    const float4* wrow = xpwT + ((size_t)k * 48 + j4) * 48;
    #pragma unroll
    for (int cc = 0; cc < 3; ++cc) {
      float4 w4 = wrow[ci + 16 * cc];
      acc[0][cc] += xr0.x * w4.x + xr0.y * w4.y + xr0.z * w4.z + xr0.w * w4.w;
      acc[1][cc] += xr1.x * w4.x + xr1.y * w4.y + xr1.z * w4.z + xr1.w * w4.w;
    }
  }
  #pragma unroll
  for (int pI = 0; pI < 2; ++pI) {
    int p = pbase + g + 16 * pI;
    int pt = ((p & 63) << 6) | (p >> 6);
    int l = (k == 0) ? p : (k == 1) ? pt : (k == 2) ? (4095 - p) : (4095 - pt);
    #pragma unroll
    for (int cc = 0; cc < 3; ++cc) {
      int c = ci + 16 * cc;
      float v = acc[pI][cc];
      if (c < 6) DTS[((size_t)bk * 6 + c) * Ll + l] = v;
      else if (c < 22) BSo[((size_t)bk * Ll + l) * Nn + (c - 6)] = v;
      else if (c < 38) CSo[((size_t)bk * Ll + l) * Nn + (c - 22)] = v;
    }
  }
}

// ---------------- dt_proj + softplus -> pixel-major DT ----------------
__global__ void dtproj_kernel(const float* __restrict__ dts, const float* __restrict__ dtw,
                              const float* __restrict__ dtb, float* __restrict__ DTo) {
  __shared__ float sdts[6][64];
  int t = threadIdx.x;
  int lb = (blockIdx.x & 63) * 64;
  int bk = blockIdx.x >> 6;
  int k = bk & 3;
  if (t < 384) {
    int r = t / 64, l = t & 63;
    sdts[r][l] = dts[((size_t)bk * 6 + r) * Ll + lb + l];
  }
  __syncthreads();
  int d = t;
  const float* wr = dtw + ((size_t)k * DI + d) * Rr;
  float w0 = wr[0], w1 = wr[1], w2 = wr[2], w3 = wr[3], w4 = wr[4], w5 = wr[5];
  float b0 = dtb[k * DI + d];
  float* ob = DTo + ((size_t)bk * Ll + lb) * DI + d;
  #pragma unroll 4
  for (int l = 0; l < 64; ++l) {
    float a = b0 + sdts[0][l] * w0 + sdts[1][l] * w1 + sdts[2][l] * w2
            + sdts[3][l] * w3 + sdts[4][l] * w4 + sdts[5][l] * w5;
    float sp = (a > 20.f) ? a : log1pf(__expf(a));
    ob[(size_t)l * DI] = sp;
  }
}

// ---------------- scan pass A: 4-deep register prefetch ----------------
__global__ void scanA_kernel(const float* __restrict__ dtg, const float* __restrict__ xc,
                             const float* __restrict__ xct, const float* __restrict__ bsg,
                             const float* __restrict__ alog,
                             float* __restrict__ P, float* __restrict__ Q) {
  int g = blockIdx.x * 256 + threadIdx.x;
  int ng = g & 3;
  int t1 = g >> 2;
  int d = t1 % DI;
  int t2 = t1 / DI;
  int c = t2 & 63;
  int bk = t2 >> 6;
  int k = bk & 3, b = bk >> 2;
  float4 al = ((const float4*)alog)[(size_t)(k * DI + d) * 4 + ng];
  float An0 = -__expf(al.x), An1 = -__expf(al.y), An2 = -__expf(al.z), An3 = -__expf(al.w);
  const float* dtp = dtg + ((size_t)bk * Ll + c * 64) * DI + d;
  const float4* bsp = (const float4*)bsg + ((size_t)bk * Ll + c * 64) * 4 + ng;
  const float* usrc = (k & 1) ? xct : xc;
  int p0 = (k >= 2) ? (4095 - c * 64) : (c * 64);
  int ustep = (k >= 2) ? -DI : DI;
  const float* up = usrc + ((size_t)b * Ll + p0) * DI + d;
  float P0 = 1.f, P1 = 1.f, P2 = 1.f, P3 = 1.f;
  float Q0 = 0.f, Q1 = 0.f, Q2 = 0.f, Q3 = 0.f;
  float dpre[4], upre[4];
  float4 bpre[4];
  #pragma unroll
  for (int i = 0; i < 4; ++i) {
    dpre[i] = dtp[(size_t)i * DI];
    upre[i] = up[(ptrdiff_t)i * ustep];
    bpre[i] = bsp[(size_t)i * 4];
  }
  for (int tg = 0; tg < 64; tg += 4) {
    #pragma unroll
    for (int i = 0; i < 4; ++i) {
      float dtv = dpre[i], u = upre[i];
      float4 Bv = bpre[i];
      int tn = tg + 4 + i;  // tail overrun: in-ws garbage, unused
      dpre[i] = dtp[(size_t)tn * DI];
      upre[i] = up[(ptrdiff_t)tn * ustep];
      bpre[i] = bsp[(size_t)tn * 4];
      float s = dtv * u;
      float a0 = __expf(dtv * An0), a1 = __expf(dtv * An1);
      float a2 = __expf(dtv * An2), a3 = __expf(dtv * An3);
      P0 *= a0; P1 *= a1; P2 *= a2; P3 *= a3;
      Q0 = Q0 * a0 + s * Bv.x; Q1 = Q1 * a1 + s * Bv.y;
      Q2 = Q2 * a2 + s * Bv.z; Q3 = Q3 * a3 + s * Bv.w;
    }
  }
  ((float4*)P)[g] = make_float4(P0, P1, P2, P3);
  ((float4*)Q)[g] = make_float4(Q0, Q1, Q2, Q3);
}

// ---------------- scan pass B ----------------
__global__ void scanB_kernel(const float* __restrict__ P, const float* __restrict__ Q,
                             float* __restrict__ H0) {
  int g = blockIdx.x * 256 + threadIdx.x;
  int n = g & 15;
  int d = (g >> 4) % DI;
  int bk = (g >> 4) / DI;
  size_t base = (size_t)bk * NC * DI * Nn + (size_t)d * Nn + n;
  float Ppre[4], Qpre[4];
  #pragma unroll
  for (int i = 0; i < 4; ++i) {
    Ppre[i] = P[base + (size_t)i * 3072];
    Qpre[i] = Q[base + (size_t)i * 3072];
  }
  float h = 0.f;
  for (int cg = 0; cg < 64; cg += 4) {
    #pragma unroll
    for (int i = 0; i < 4; ++i) {
      float pv = Ppre[i], qv = Qpre[i];
      Ppre[i] = P[base + (size_t)(cg + 4 + i) * 3072];
      Qpre[i] = Q[base + (size_t)(cg + 4 + i) * 3072];
      H0[base + (size_t)(cg + i) * 3072] = h;
      h = pv * h + qv;
    }
  }
}

// ---------------- scan pass C: 4-deep register prefetch ----------------
__global__ void scanC_kernel(const float* __restrict__ dtg, const float* __restrict__ xc,
                             const float* __restrict__ xct, const float* __restrict__ bsg,
                             const float* __restrict__ csg, const float* __restrict__ alog,
                             const float* __restrict__ Dsv_, const float* __restrict__ H0,
                             float* __restrict__ outy) {
  int g = blockIdx.x * 256 + threadIdx.x;
  int ng = g & 3;
  int t1 = g >> 2;
  int d = t1 % DI;
  int t2 = t1 / DI;
  int c = t2 & 63;
  int bk = t2 >> 6;
  int k = bk & 3, b = bk >> 2;
  float4 al = ((const float4*)alog)[(size_t)(k * DI + d) * 4 + ng];
  float An0 = -__expf(al.x), An1 = -__expf(al.y), An2 = -__expf(al.z), An3 = -__expf(al.w);
  float Dsv = Dsv_[k * DI + d];
  const float* dtp = dtg + ((size_t)bk * Ll + c * 64) * DI + d;
  const float4* bsp = (const float4*)bsg + ((size_t)bk * Ll + c * 64) * 4 + ng;
  const float4* csp = (const float4*)csg + ((size_t)bk * Ll + c * 64) * 4 + ng;
  const float* usrc = (k & 1) ? xct : xc;
  int p0 = (k >= 2) ? (4095 - c * 64) : (c * 64);
  int ustep = (k >= 2) ? -DI : DI;
  const float* up = usrc + ((size_t)b * Ll + p0) * DI + d;
  float* yo = outy + ((size_t)bk * Ll + c * 64) * DI + d;
  float4 h4 = ((const float4*)H0)[g];
  float h0 = h4.x, h1 = h4.y, h2 = h4.z, h3 = h4.w;
  float dpre[4], upre[4];
  float4 bpre[4], cpre[4];
  #pragma unroll
  for (int i = 0; i < 4; ++i) {
    dpre[i] = dtp[(size_t)i * DI];
    upre[i] = up[(ptrdiff_t)i * ustep];
    bpre[i] = bsp[(size_t)i * 4];
    cpre[i] = csp[(size_t)i * 4];
  }
  for (int tg = 0; tg < 64; tg += 4) {
    #pragma unroll
    for (int i = 0; i < 4; ++i) {
      float dtv = dpre[i], u = upre[i];
      float4 Bv = bpre[i], Cv = cpre[i];
      int tn = tg + 4 + i;  // tail overrun: in-ws garbage, unused
      dpre[i] = dtp[(size_t)tn * DI];
      upre[i] = up[(ptrdiff_t)tn * ustep];
      bpre[i] = bsp[(size_t)tn * 4];
      cpre[i] = csp[(size_t)tn * 4];
      float s = dtv * u;
      float a0 = __expf(dtv * An0), a1 = __expf(dtv * An1);
      float a2 = __expf(dtv * An2), a3 = __expf(dtv * An3);
      h0 = h0 * a0 + s * Bv.x; h1 = h1 * a1 + s * Bv.y;
      h2 = h2 * a2 + s * Bv.z; h3 = h3 * a3 + s * Bv.w;
      float yp = h0 * Cv.x + h1 * Cv.y + h2 * Cv.z + h3 * Cv.w;
      yp = qadd1(yp);
      yp = qadd2(yp);
      if (ng == 0) yo[(size_t)(tg + i) * DI] = yp + u * Dsv;
    }
  }
}

// ---------------- FFT branch (transposed intermediates) ----------------
__global__ void dft_row_kernel(const float* __restrict__ xf, float* __restrict__ Tr,
                               float* __restrict__ Ti) {
  __shared__ float row[4][64];
  __shared__ float cs[64], sn[64];
  int t = threadIdx.x, lane = t & 63, wv = t >> 6;
  int bch = blockIdx.x * 4 + wv;
  int h = bch & 63, bc = bch >> 6;
  row[wv][lane] = xf[(size_t)bch * 64 + lane];
  if (t < 64) {
    float ang = (float)t * 0.09817477042468103f;
    float s0, c0; sincosf(ang, &s0, &c0); sn[t] = s0; cs[t] = c0;
  }
  __syncthreads();
  if (lane < 33) {
    float ar = 0.f, ai = 0.f;
    for (int wq = 0; wq < 64; ++wq) {
      int j = (lane * wq) & 63;
      ar += row[wv][wq] * cs[j];
      ai -= row[wv][wq] * sn[j];
    }
    Tr[((size_t)bc * 33 + lane) * 64 + h] = ar;
    Ti[((size_t)bc * 33 + lane) * 64 + h] = ai;
  }
}

__global__ void dft_col_kernel(const float* __restrict__ Tr, const float* __restrict__ Ti,
                               float* __restrict__ Gr, float* __restrict__ Gi) {
  __shared__ float tr[4][64], ti[4][64];
  __shared__ float cs[64], sn[64];
  int t = threadIdx.x, lane = t & 63, wv = t >> 6;
  int idx = blockIdx.x * 4 + wv;
  int v = idx % 33, bc = idx / 33;
  tr[wv][lane] = Tr[((size_t)bc * 33 + v) * 64 + lane];
  ti[wv][lane] = Ti[((size_t)bc * 33 + v) * 64 + lane];
  if (t < 64) {
    float ang = (float)t * 0.09817477042468103f;
    float s0, c0; sincosf(ang, &s0, &c0); sn[t] = s0; cs[t] = c0;
  }
  __syncthreads();
  float ar = 0.f, ai = 0.f;
  for (int hh = 0; hh < 64; ++hh) {
    int j = (lane * hh) & 63;
    ar += tr[wv][hh] * cs[j] + ti[wv][hh] * sn[j];
    ai += ti[wv][hh] * cs[j] - tr[wv][hh] * sn[j];
  }
  Gr[((size_t)bc * 64 + lane) * 33 + v] = ar * (1.f / 64.f);
  Gi[((size_t)bc * 64 + lane) * 33 + v] = ai * (1.f / 64.f);
}

__global__ void fmix2_kernel(const float* __restrict__ Gr, const float* __restrict__ Gi,
                             const float* __restrict__ w, const float* __restrict__ bias,
                             float* __restrict__ Mr, float* __restrict__ Mi) {
  __shared__ float xs[16][100];
  int t = threadIdx.x;
  int uvb = (blockIdx.x % 132) * 16;
  int b = blockIdx.x / 132;
  for (int idx = t; idx < 96 * 16; idx += 256) {
    int ch = idx >> 4, px = idx & 15;
    const float* src = (ch & 1) ? Gi : Gr;
    xs[px][ch] = src[((size_t)(b * 48 + (ch >> 1))) * 2112 + uvb + px];
  }
  __syncthreads();
  int px = t >> 4, ci = t & 15;
  float acc[6];
  #pragma unroll
  for (int cc = 0; cc < 6; ++cc) acc[cc] = bias[ci + 16 * cc];
  const float4* xr4 = (const float4*)&xs[px][0];
  #pragma unroll 2
  for (int j4 = 0; j4 < 24; ++j4) {
    float4 x4 = xr4[j4];
    #pragma unroll
    for (int cc = 0; cc < 6; ++cc) {
      float4 w4 = ((const float4*)w)[(size_t)(ci + 16 * cc) * 24 + j4];
      acc[cc] += x4.x * w4.x + x4.y * w4.y + x4.z * w4.z + x4.w * w4.w;
    }
  }
  int uv = uvb + px;
  int u = uv / 33, vv2 = uv % 33;
  #pragma unroll
  for (int cc = 0; cc < 6; ++cc) {
    int o = ci + 16 * cc;
    float v = silu_(acc[cc]);
    float* dst = (o & 1) ? Mi : Mr;
    dst[((size_t)(b * 48 + (o >> 1))) * 2112 + vv2 * 64 + u] = v;
  }
}

__global__ void idft_col_kernel(const float* __restrict__ Mr, const float* __restrict__ Mi,
                                float* __restrict__ gr, float* __restrict__ gi) {
  __shared__ float mr[4][64], mi[4][64];
  __shared__ float cs[64], sn[64];
  int t = threadIdx.x, lane = t & 63, wv = t >> 6;
  int idx = blockIdx.x * 4 + wv;
  int v = idx % 33, bc = idx / 33;
  mr[wv][lane] = Mr[((size_t)bc * 33 + v) * 64 + lane];
  mi[wv][lane] = Mi[((size_t)bc * 33 + v) * 64 + lane];
  if (t < 64) {
    float ang = (float)t * 0.09817477042468103f;
    float s0, c0; sincosf(ang, &s0, &c0); sn[t] = s0; cs[t] = c0;
  }
  __syncthreads();
  float ar = 0.f, ai = 0.f;
  for (int u = 0; u < 64; ++u) {
    int j = (lane * u) & 63;
    ar += mr[wv][u] * cs[j] - mi[wv][u] * sn[j];
    ai += mr[wv][u] * sn[j] + mi[wv][u] * cs[j];
  }
  gr[((size_t)bc * 64 + lane) * 33 + v] = ar;
  gi[((size_t)bc * 64 + lane) * 33 + v] = ai;
}

__global__ void irfft_row_kernel(const float* __restrict__ gr, const float* __restrict__ gi,
                                 float* __restrict__ ysp) {
  __shared__ float r[4][33], im[4][33];
  __shared__ float cs[64], sn[64];
  int t = threadIdx.x, lane = t & 63, wv = t >> 6;
  int bch = blockIdx.x * 4 + wv;
  if (lane < 33) {
    r[wv][lane] = gr[(size_t)bch * 33 + lane];
    im[wv][lane] = gi[(size_t)bch * 33 + lane];
  }
  if (t < 64) {
    float ang = (float)t * 0.09817477042468103f;
    float s0, c0; sincosf(ang, &s0, &c0); sn[t] = s0; cs[t] = c0;
  }
  __syncthreads();
  float acc = r[wv][0] + ((lane & 1) ? -r[wv][32] : r[wv][32]);
  for (int v = 1; v < 32; ++v) {
    int j = (v * lane) & 63;
    acc += 2.f * (r[wv][v] * cs[j] - im[wv][v] * sn[j]);
  }
  ysp[(size_t)bch * 64 + lane] = acc * (1.f / 64.f);
}

// ---------------- MGCB depthwise + gelu gate (float4 channels) ----------------
__global__ void mgcb_dw_kernel(const float* __restrict__ pm, const float* __restrict__ w3t,
                               const float* __restrict__ w5t, float* __restrict__ ymg) {
  int idx = blockIdx.x * 256 + threadIdx.x;
  int c4 = idx % 48;
  int p = (idx / 48) & (Ll - 1);
  int b = idx / (48 * Ll);
  int h = p >> 6, wq = p & 63;
  const float4* base = (const float4*)pm + (size_t)b * Ll * 96;
  const float4* wt3 = (const float4*)w3t;
  float g0 = 0.f, g1 = 0.f, g2 = 0.f, g3 = 0.f;
  float m0 = 0.f, m1 = 0.f, m2 = 0.f, m3 = 0.f;
  if (c4 < 24) {
    #pragma unroll
    for (int i = 0; i < 3; ++i) {
      int hh = h - 1 + i; if ((unsigned)hh >= 64u) continue;
      #pragma unroll
      for (int j = 0; j < 3; ++j) {
        int ww2 = wq - 1 + j; if ((unsigned)ww2 >= 64u) continue;
        const float4* px = base + (size_t)(hh * 64 + ww2) * 96;
        float4 xg = px[c4];
        float4 wg = wt3[(i * 3 + j) * 72 + c4];
        g0 += xg.x * wg.x; g1 += xg.y * wg.y; g2 += xg.z * wg.z; g3 += xg.w * wg.w;
        float4 xm = px[48 + c4];
        float4 wm = wt3[(i * 3 + j) * 72 + 48 + c4];
        m0 += xm.x * wm.x; m1 += xm.y * wm.y; m2 += xm.z * wm.z; m3 += xm.w * wm.w;
      }
    }
  } else {
    #pragma unroll
    for (int i = 0; i < 3; ++i) {
      int hh = h - 1 + i; if ((unsigned)hh >= 64u) continue;
      #pragma unroll
      for (int j = 0; j < 3; ++j) {
        int ww2 = wq - 1 + j; if ((unsigned)ww2 >= 64u) continue;
        float4 xg = base[(size_t)(hh * 64 + ww2) * 96 + c4];
        float4 wg = wt3[(i * 3 + j) * 72 + c4];
        g0 += xg.x * wg.x; g1 += xg.y * wg.y; g2 += xg.z * wg.z; g3 += xg.w * wg.w;
      }
    }
    const float4* wt5 = (const float4*)w5t;
    int cw4 = c4 - 24;
    #pragma unroll
    for (int i = 0; i < 5; ++i) {
      int hh = h - 2 + i; if ((unsigned)hh >= 64u) continue;
      #pragma unroll
      for (int j = 0; j < 5; ++j) {
        int ww2 = wq - 2 + j; if ((unsigned)ww2 >= 64u) continue;
        float4 xm = base[(size_t)(hh * 64 + ww2) * 96 + 48 + c4];
        float4 wm = wt5[(i * 5 + j) * 24 + cw4];
        m0 += xm.x * wm.x; m1 += xm.y * wm.y; m2 += xm.z * wm.z; m3 += xm.w * wm.w;
      }
    }
  }
  const float IS2 = 0.70710678118654752f;
  float4 o;
  o.x = 0.5f * g0 * (1.f + erff(g0 * IS2)) * m0;
  o.y = 0.5f * g1 * (1.f + erff(g1 * IS2)) * m1;
  o.z = 0.5f * g2 * (1.f + erff(g2 * IS2)) * m2;
  o.w = 0.5f * g3 * (1.f + erff(g3 * IS2)) * m3;
  ((float4*)ymg)[idx] = o;
}

// ---------------- final (float4) ----------------
__global__ void final_kernel(const float* __restrict__ xres, const float* __restrict__ yc,
                             const float* __restrict__ ss2, const float* __restrict__ avec,
                             float* __restrict__ out) {
  int i4 = blockIdx.x * 256 + threadIdx.x;   // 196608 float4
  int e0 = i4 * 4;
  int c = e0 % 96;
  int b = e0 / (Ll * 96);
  float4 xr = ((const float4*)xres)[i4];
  float4 yv = ((const float4*)yc)[i4];
  const float* av = avec + b * 96 + c;
  const float* sv = ss2 + c;
  float4 o;
  o.x = xr.x * sv[0] + yv.x * av[0];
  o.y = xr.y * sv[1] + yv.y * av[1];
  o.z = xr.z * sv[2] + yv.z * av[2];
  o.w = xr.w * sv[3] + yv.w * av[3];
  ((float4*)out)[i4] = o;
}

// ---------------- host ----------------
extern "C" void kernel_launch(void* const* d_in, const int* in_sizes, int n_in,
                              void* d_out, int out_size, void* d_ws, size_t ws_size,
                              hipStream_t stream) {
  const float* input      = (const float*)d_in[0];
  const float* ln1_g      = (const float*)d_in[1];
  const float* ln1_b      = (const float*)d_in[2];
  const float* skip_scale = (const float*)d_in[3];
  const float* skip_scale2= (const float*)d_in[4];
  const float* ln2_g      = (const float*)d_in[5];
  const float* ln2_b      = (const float*)d_in[6];
  const float* in_proj_w  = (const float*)d_in[7];
  const float* conv2d_w   = (const float*)d_in[8];
  const float* conv2d_b   = (const float*)d_in[9];
  const float* x_proj_w   = (const float*)d_in[10];
  const float* dt_proj_w  = (const float*)d_in[11];
  const float* dt_proj_b  = (const float*)d_in[12];
  const float* A_logs     = (const float*)d_in[13];
  const float* Ds         = (const float*)d_in[14];
  const float* out_norm_g = (const float*)d_in[15];
  const float* out_norm_b = (const float*)d_in[16];
  const float* out_proj_w = (const float*)d_in[17];
  const float* f1_w       = (const float*)d_in[18];
  const float* f1_b       = (const float*)d_in[19];
  const float* fm_w       = (const float*)d_in[20];
  const float* fm_b       = (const float*)d_in[21];
  const float* f2_w       = (const float*)d_in[22];
  const float* f2_b       = (const float*)d_in[23];
  const float* mg_in_w    = (const float*)d_in[24];
  const float* mg_dw3_w   = (const float*)d_in[25];
  const float* mg_dw5_w   = (const float*)d_in[26];
  const float* mg_out_w   = (const float*)d_in[27];
  const float* ca_w1      = (const float*)d_in[28];
  const float* ca_b1      = (const float*)d_in[29];
  const float* ca_w2      = (const float*)d_in[30];
  const float* ca_b2      = (const float*)d_in[31];

  float* W = (float*)d_ws;
  float* XN    = W;                     // 786432 (spare)
  float* ZSILU = XN + 786432;           // 1572864
  float* XX    = ZSILU + 1572864;       // 1572864
  float* XC    = XX + 1572864;          // 1572864
  float* XCT   = XC + 1572864;          // 1572864
  float* DT    = XCT + 1572864;         // 6291456
  float* BSb   = DT + 6291456;          // 524288
  float* CSb   = BSb + 524288;          // 524288
  float* PP    = CSb + 524288;          // 1572864
  float* QQ    = PP + 1572864;          // 1572864
  float* H0    = QQ + 1572864;          // 1572864
  float* OUTY  = H0 + 1572864;          // 6291456
  float* YGATE = OUTY + 6291456;        // 1572864 (spare)
  float* ATTN  = YGATE + 1572864;       // 786432 (spare)
  float* FFTOUT= ATTN + 786432;         // 786432
  float* XRES  = FFTOUT + 786432;       // 786432
  float* XN2   = XRES + 786432;         // 786432
  float* MEANS = XN2 + 786432;          // 192 (spare)
  float* AVEC  = MEANS + 192;           // 192
  float* XPWT  = AVEC + 192;            // 36864
  float* WC3T  = XPWT + 36864;          // 1728
  float* W3T   = WC3T + 1728;           // 2592
  float* W5T   = W3T + 2592;            // 2400
  float* CAP   = W5T + 2400;            // 24576
  float* WIPT  = CAP + 24576;           // 36864
  float* WMGT  = WIPT + 36864;          // 36864
  float* WOPT  = WMGT + 36864;          // 18432
  float* WMOT  = WOPT + 18432;          // 18432
  float* WF1T  = WMOT + 18432;          // 4608
  float* WF2T  = WF1T + 4608;           // 4608
  float* DTS = H0;
  float* XF  = PP;                      // 393216
  float* TR  = XF + 393216;
  float* TI  = TR + 202752;
  float* GR  = TI + 202752;
  float* GI  = GR + 202752;
  float* MR  = TR;
  float* MI  = TI;
  float* G2R = GR;
  float* G2I = GI;
  float* YSP = GI + 202752;
  float* PMG = DT;
  float* YMG = DT + 3145728;
  float* YCb = YMG + 1572864;

  wprep_all_kernel<<<36, 256, 0, stream>>>(
      x_proj_w, (float4*)XPWT, conv2d_w, mg_dw3_w, mg_dw5_w, WC3T, W3T, W5T,
      in_proj_w, (float4*)WIPT, mg_in_w, (float4*)WMGT, out_proj_w, (float4*)WOPT,
      mg_out_w, (float4*)WMOT, f1_w, (float4*)WF1T, f2_w, (float4*)WF2T);
  conv1x1v2_kernel<96, 384, 96, 64, 0, 2, 0, 0, 1><<<512, 256, 0, stream>>>(
      input, (const float4*)WIPT, nullptr, XX, ZSILU, ln1_g, ln1_b);
  dwconv3_silu_kernel<<<1536, 256, 0, stream>>>(XX, WC3T, conv2d_b, XC, XCT);
  proj_kernel<<<1024, 256, 0, stream>>>(XC, (const float4*)XPWT, BSb, CSb, DTS);
  dtproj_kernel<<<512, 192, 0, stream>>>(DTS, dt_proj_w, dt_proj_b, DT);
  scanA_kernel<<<1536, 256, 0, stream>>>(DT, XC, XCT, BSb, A_logs, PP, QQ);
  scanB_kernel<<<96, 256, 0, stream>>>(PP, QQ, H0);
  conv1x1v2_kernel<96, 48, 48, 32, 0, 1, 1, 1, 1><<<256, 256, 0, stream>>>(
      input, (const float4*)WF1T, f1_b, XF, nullptr, ln1_g, ln1_b);
  dft_row_kernel<<<1536, 256, 0, stream>>>(XF, TR, TI);
  dft_col_kernel<<<792, 256, 0, stream>>>(TR, TI, GR, GI);
  fmix2_kernel<<<264, 256, 0, stream>>>(GR, GI, fm_w, fm_b, MR, MI);
  idft_col_kernel<<<792, 256, 0, stream>>>(MR, MI, G2R, G2I);
  irfft_row_kernel<<<1536, 256, 0, stream>>>(G2R, G2I, YSP);
  conv1x1v2_kernel<48, 96, 96, 32, 1, 0, 0, 1, 0><<<256, 256, 0, stream>>>(
      YSP, (const float4*)WF2T, f2_b, FFTOUT, nullptr, nullptr, nullptr);
  scanC_kernel<<<1536, 256, 0, stream>>>(DT, XC, XCT, BSb, CSb, A_logs, Ds, H0, OUTY);
  outproj_fused_kernel<<<256, 256, 0, stream>>>(
      OUTY, ZSILU, out_norm_g, out_norm_b, (const float4*)WOPT, input, FFTOUT,
      skip_scale, ln2_g, ln2_b, XRES, XN2);
  conv1x1v2_kernel<96, 384, 96, 64, 0, 0, 0, 0, 0><<<512, 256, 0, stream>>>(
      XN2, (const float4*)WMGT, nullptr, PMG, nullptr, nullptr, nullptr);
  mgcb_dw_kernel<<<1536, 256, 0, stream>>>(PMG, W3T, W5T, YMG);
  mgout_fused_kernel<<<256, 256, 0, stream>>>(YMG, (const float4*)WMOT, YCb, CAP);
  camerge_kernel<<<1, 768, 0, stream>>>(CAP, ca_w1, ca_b1, ca_w2, ca_b2, AVEC);
  final_kernel<<<768, 256, 0, stream>>>(XRES, YCb, skip_scale2, AVEC, (float*)d_out);
}